// Round 3
// baseline (432.425 us; speedup 1.0000x reference)
//
#include <hip/hip_runtime.h>
#include <math.h>

// Problem constants (from reference): D=2048, E=8, T=32768, top_k=2
constexpr int D_DIM = 2048;
constexpr int NEXP  = 8;
constexpr int NTOK  = 32768;
constexpr int TT    = 4;    // tokens per wave
constexpr int KC    = 128;  // k per chunk: 32 lane-pairs x 4 consecutive k
constexpr int WPB   = 4;    // waves per block (block = 256 threads)

typedef float vf4 __attribute__((ext_vector_type(4)));

__device__ __forceinline__ float softplus_f(float x) {
    return (x > 20.0f) ? x : log1pf(expf(x));
}

__global__ __launch_bounds__(256, 4)   // <=128 VGPR; live set ~108 so no spill
void noisy_topk_router(const float* __restrict__ h,
                       const float* __restrict__ Ww,
                       const float* __restrict__ bw,
                       const float* __restrict__ Wn,
                       const float* __restrict__ bn,
                       const float* __restrict__ eps,
                       float* __restrict__ out_sparse,
                       float* __restrict__ out_ix,
                       float* __restrict__ out_full)
{
    const int lane = threadIdx.x & 63;
    const int wave = threadIdx.x >> 6;
    const int t0   = (blockIdx.x * WPB + wave) * TT;
    const int role = lane & 1;     // 0 -> W_w experts 0..7, 1 -> W_n experts 0..7
    const int kg   = lane >> 1;    // k-group: owns k = 4*kg .. 4*kg+3 within a chunk

    // p[t*8+o]: partial dot for (token t0+t, expert-col o of this lane's matrix)
    float p[TT * 8];
#pragma unroll
    for (int i = 0; i < TT * 8; ++i) p[i] = 0.0f;

    const float* __restrict__ Wp = role ? Wn : Ww;
    const float* hbase = h + (size_t)t0 * D_DIM + 4 * kg;

    // prefetch h for chunk 0 (nontemporal: h is read-once, keep it out of L2)
    vf4 hv[TT];
#pragma unroll
    for (int t = 0; t < TT; ++t)
        hv[t] = __builtin_nontemporal_load((const vf4*)(hbase + (size_t)t * D_DIM));

#pragma unroll 1
    for (int k0 = 0; k0 < D_DIM; k0 += KC) {
        // W rows k0+4kg .. +3 of this lane's matrix: 4 rows x 8 floats = 128 B contiguous
        const vf4* wp = (const vf4*)(Wp + (size_t)(k0 + 4 * kg) * NEXP);
        vf4 w0 = wp[0], w1 = wp[1], w2 = wp[2], w3 = wp[3],
            w4 = wp[4], w5 = wp[5], w6 = wp[6], w7 = wp[7];

        // prefetch next chunk's h
        vf4 hvn[TT];
        if (k0 + KC < D_DIM) {
#pragma unroll
            for (int t = 0; t < TT; ++t)
                hvn[t] = __builtin_nontemporal_load(
                    (const vf4*)(hbase + (size_t)t * D_DIM + (k0 + KC)));
        }

        const float w[32] = {w0[0], w0[1], w0[2], w0[3], w1[0], w1[1], w1[2], w1[3],
                             w2[0], w2[1], w2[2], w2[3], w3[0], w3[1], w3[2], w3[3],
                             w4[0], w4[1], w4[2], w4[3], w5[0], w5[1], w5[2], w5[3],
                             w6[0], w6[1], w6[2], w6[3], w7[0], w7[1], w7[2], w7[3]};

#pragma unroll
        for (int t = 0; t < TT; ++t) {
#pragma unroll
            for (int d = 0; d < 4; ++d) {
                const float x = hv[t][d];
#pragma unroll
                for (int o = 0; o < 8; ++o)
                    p[t * 8 + o] = fmaf(x, w[d * 8 + o], p[t * 8 + o]);
            }
        }

#pragma unroll
        for (int t = 0; t < TT; ++t) hv[t] = hvn[t];
    }

    // Compacting reduce-scatter over the 32 k-groups (lane bits 1..5; bit 0 = role).
    // Invariant before step s: compact j holds v=(j<<s)|((lane>>1)&((1<<s)-1)).
    // After 5 steps lane L holds p[0] = value v = L>>1 = t*8 + o, for matrix role L&1.
#pragma unroll
    for (int s = 0; s < 5; ++s) {
        const int m = 2 << s;
        const bool hi = (lane & m) != 0;
        const int n = 32 >> (s + 1);
#pragma unroll
        for (int j = 0; j < n; ++j) {
            float a  = p[2 * j];
            float b  = p[2 * j + 1];
            float ta = __shfl_xor(a, m, 64);
            float tb = __shfl_xor(b, m, 64);
            p[j] = hi ? (b + tb) : (a + ta);
        }
    }

    // Epilogue: lane L -> token t0 + (L>>4), expert o = (L>>1)&7, matrix = L&1.
    const int  o         = (lane >> 1) & 7;
    const bool noiseLane = (role != 0);
    const int  tok       = t0 + (lane >> 4);
    const float bias     = noiseLane ? bn[o] : bw[o];

    const float val = p[0] + bias;              // logit (role 0) or noise-logit (role 1)
    const float sp  = softplus_f(val);
    const float spN = __shfl_xor(sp, 1, 64);    // logit lane <- partner's softplus
    const float ev  = eps[(size_t)tok * NEXP + o];
    const float noisy = val + ev * spN;         // meaningful on logit lanes

    // argmax over the 8 logit lanes (same token, role 0): masks {2,4,8}
    float v0 = noisy; int i0 = o;
#pragma unroll
    for (int m = 2; m <= 8; m <<= 1) {
        float ov = __shfl_xor(v0, m, 64);
        int   oi = __shfl_xor(i0, m, 64);
        bool take = (ov > v0) || (ov == v0 && oi < i0);
        v0 = take ? ov : v0;
        i0 = take ? oi : i0;
    }
    // second argmax (exclude i0)
    float v1 = (o == i0) ? -INFINITY : noisy; int i1 = o;
#pragma unroll
    for (int m = 2; m <= 8; m <<= 1) {
        float ov = __shfl_xor(v1, m, 64);
        int   oi = __shfl_xor(i1, m, 64);
        bool take = (ov > v1) || (ov == v1 && oi < i1);
        v1 = take ? ov : v1;
        i1 = take ? oi : i1;
    }
    // full softmax over 8 experts
    const float ex = expf(noisy - v0);
    float ssum = ex;
#pragma unroll
    for (int m = 2; m <= 8; m <<= 1) ssum += __shfl_xor(ssum, m, 64);
    const float fullv = ex / ssum;
    // sparse softmax over the top-2 (others exactly 0)
    const float dd  = expf(v1 - v0);
    const float den = 1.0f + dd;
    const float sparsev = (o == i0) ? (1.0f / den)
                        : (o == i1) ? (dd / den) : 0.0f;

    if (!noiseLane) {
        out_sparse[(size_t)tok * NEXP + o] = sparsev;
        out_full  [(size_t)tok * NEXP + o] = fullv;
        if (o == 0) {
            out_ix[(size_t)tok * 2]     = (float)i0;
            out_ix[(size_t)tok * 2 + 1] = (float)i1;
        }
    }
}

extern "C" void kernel_launch(void* const* d_in, const int* in_sizes, int n_in,
                              void* d_out, int out_size, void* d_ws, size_t ws_size,
                              hipStream_t stream) {
    const float* h   = (const float*)d_in[0];
    const float* Ww  = (const float*)d_in[1];
    const float* bw  = (const float*)d_in[2];
    const float* Wn  = (const float*)d_in[3];
    const float* bn  = (const float*)d_in[4];
    const float* eps = (const float*)d_in[5];
    // d_in[6] = top_k (always 2 for this problem)

    float* out_sparse = (float*)d_out;                         // [T, 8]
    float* out_ix     = out_sparse + (size_t)NTOK * NEXP;      // [T, 2] (as float)
    float* out_full   = out_ix + (size_t)NTOK * 2;             // [T, 8]

    const int grid = NTOK / (TT * WPB);  // 2048 blocks x 256 threads
    noisy_topk_router<<<grid, 256, 0, stream>>>(h, Ww, bw, Wn, bn, eps,
                                                out_sparse, out_ix, out_full);
}

// Round 4
// 371.253 us; speedup vs baseline: 1.1648x; 1.1648x over previous
//
#include <hip/hip_runtime.h>
#include <math.h>

// Problem constants (from reference): D=2048, E=8, T=32768, top_k=2
constexpr int D_DIM = 2048;
constexpr int NEXP  = 8;
constexpr int NTOK  = 32768;
constexpr int TT    = 4;             // tokens per wave
constexpr int KC    = 128;           // k rows per chunk: 32 kg-pairs x 4 rows
constexpr int NCH   = D_DIM / KC;    // 16 chunks
constexpr int WPB   = 4;             // waves per block (256 threads)

// LDS W staging: 2 bufs x 2 matrices x 32 kg x (32 data + 1 pad) floats
constexpr int KGSTR = 33;            // +1 float pad -> banks (kg + j) % 32, conflict-free
constexpr int MSTR  = 32 * KGSTR;    // 1056 floats per matrix  (1056 % 32 == 0 -> role = 2-way, free)
constexpr int BSTR  = 2 * MSTR;      // 2112 floats per buffer

typedef float vf4 __attribute__((ext_vector_type(4)));

__device__ __forceinline__ float softplus_f(float x) {
    return (x > 20.0f) ? x : log1pf(expf(x));
}

__global__ __launch_bounds__(256, 4)   // ~115 VGPR live set -> true 4 waves/SIMD
void noisy_topk_router(const float* __restrict__ h,
                       const float* __restrict__ Ww,
                       const float* __restrict__ bw,
                       const float* __restrict__ Wn,
                       const float* __restrict__ bn,
                       const float* __restrict__ eps,
                       float* __restrict__ out_sparse,
                       float* __restrict__ out_ix,
                       float* __restrict__ out_full)
{
    __shared__ float sW[2 * BSTR];   // 16896 B

    const int tid  = threadIdx.x;
    const int lane = tid & 63;
    const int wave = tid >> 6;
    const int t0   = (blockIdx.x * WPB + wave) * TT;
    const int role = lane & 1;       // 0 -> W_w, 1 -> W_n
    const int kg   = lane >> 1;      // owns rows 4kg..4kg+3 within each chunk

    // Staging assignment: this thread stages float4 #tid of matrix 0 and #tid of matrix 1.
    const int s_kg   = tid >> 3;     // tid 0..255 -> kg 0..31 per... (tid&255)>>3
    const int s_slot = tid & 7;
    const int s_dst0 = 0 * MSTR + (s_kg & 31) * KGSTR + s_slot * 4;  // within-buffer float idx, m=0
    const int s_dst1 = 1 * MSTR + (s_kg & 31) * KGSTR + s_slot * 4;  // m=1
    const int s_src  = (tid & 255) * 4;                               // float offset within chunk span

    // p[t*8+o]: partial dot for (token t0+t, expert o of this lane's matrix)
    float p[TT * 8];
#pragma unroll
    for (int i = 0; i < TT * 8; ++i) p[i] = 0.0f;

    const float* hbase = h + (size_t)t0 * D_DIM + 4 * kg;

    // ---- stage chunk 0 into buffer 0 ----
    {
        vf4 a = *(const vf4*)(Ww + s_src);
        vf4 b = *(const vf4*)(Wn + s_src);
#pragma unroll
        for (int i = 0; i < 4; ++i) sW[s_dst0 + i] = a[i];
#pragma unroll
        for (int i = 0; i < 4; ++i) sW[s_dst1 + i] = b[i];
    }
    // prefetch h for chunk 0
    vf4 hv[TT];
#pragma unroll
    for (int t = 0; t < TT; ++t)
        hv[t] = *(const vf4*)(hbase + (size_t)t * D_DIM);
    __syncthreads();

#pragma unroll 1
    for (int c = 0; c < NCH; ++c) {
        const int cur = c & 1;
        const bool more = (c + 1 < NCH);

        // global loads for next chunk's W (into regs; LDS write after compute reads issue)
        vf4 wa, wb;
        if (more) {
            const int src = (c + 1) * (KC * NEXP) + s_src;
            wa = *(const vf4*)(Ww + src);
            wb = *(const vf4*)(Wn + src);
        }
        // prefetch next chunk's h
        vf4 hvn[TT];
        if (more) {
#pragma unroll
            for (int t = 0; t < TT; ++t)
                hvn[t] = *(const vf4*)(hbase + (size_t)t * D_DIM + (c + 1) * KC);
        }

        // read this lane's W slice from LDS: 32 floats (4 rows x 8 experts)
        const int rbase = cur * BSTR + role * MSTR + kg * KGSTR;
        float w[32];
#pragma unroll
        for (int j = 0; j < 32; ++j) w[j] = sW[rbase + j];

#pragma unroll
        for (int t = 0; t < TT; ++t) {
#pragma unroll
            for (int r = 0; r < 4; ++r) {
                const float x = hv[t][r];
#pragma unroll
                for (int o = 0; o < 8; ++o)
                    p[t * 8 + o] = fmaf(x, w[r * 8 + o], p[t * 8 + o]);
            }
        }

        // write next chunk's W into the other buffer
        if (more) {
            const int obase = (cur ^ 1) * BSTR;
#pragma unroll
            for (int i = 0; i < 4; ++i) sW[obase + s_dst0 + i] = wa[i];
#pragma unroll
            for (int i = 0; i < 4; ++i) sW[obase + s_dst1 + i] = wb[i];
#pragma unroll
            for (int t = 0; t < TT; ++t) hv[t] = hvn[t];
        }
        __syncthreads();
    }

    // Compacting reduce-scatter over the 32 k-groups (lane bits 1..5; bit 0 = role).
    // After 5 steps lane L holds p[0] = value t*8+o (t = L>>4, o = (L>>1)&7) for matrix L&1.
#pragma unroll
    for (int s = 0; s < 5; ++s) {
        const int m = 2 << s;
        const bool hi = (lane & m) != 0;
        const int n = 32 >> (s + 1);
#pragma unroll
        for (int j = 0; j < n; ++j) {
            float a  = p[2 * j];
            float b  = p[2 * j + 1];
            float ta = __shfl_xor(a, m, 64);
            float tb = __shfl_xor(b, m, 64);
            p[j] = hi ? (b + tb) : (a + ta);
        }
    }

    // Epilogue: lane L -> token t0 + (L>>4), expert o = (L>>1)&7, matrix = L&1.
    const int  o         = (lane >> 1) & 7;
    const bool noiseLane = (role != 0);
    const int  tok       = t0 + (lane >> 4);
    const float bias     = noiseLane ? bn[o] : bw[o];

    const float val = p[0] + bias;              // logit (role 0) or noise-logit (role 1)
    const float sp  = softplus_f(val);
    const float spN = __shfl_xor(sp, 1, 64);    // logit lane <- partner's softplus
    const float ev  = eps[(size_t)tok * NEXP + o];
    const float noisy = val + ev * spN;         // meaningful on logit lanes

    // argmax over the 8 logit lanes (same token, role 0): masks {2,4,8}
    float v0 = noisy; int i0 = o;
#pragma unroll
    for (int m = 2; m <= 8; m <<= 1) {
        float ov = __shfl_xor(v0, m, 64);
        int   oi = __shfl_xor(i0, m, 64);
        bool take = (ov > v0) || (ov == v0 && oi < i0);
        v0 = take ? ov : v0;
        i0 = take ? oi : i0;
    }
    // second argmax (exclude i0)
    float v1 = (o == i0) ? -INFINITY : noisy; int i1 = o;
#pragma unroll
    for (int m = 2; m <= 8; m <<= 1) {
        float ov = __shfl_xor(v1, m, 64);
        int   oi = __shfl_xor(i1, m, 64);
        bool take = (ov > v1) || (ov == v1 && oi < i1);
        v1 = take ? ov : v1;
        i1 = take ? oi : i1;
    }
    // full softmax over 8 experts
    const float ex = expf(noisy - v0);
    float ssum = ex;
#pragma unroll
    for (int m = 2; m <= 8; m <<= 1) ssum += __shfl_xor(ssum, m, 64);
    const float fullv = ex / ssum;
    // sparse softmax over the top-2 (others exactly 0)
    const float dd  = expf(v1 - v0);
    const float den = 1.0f + dd;
    const float sparsev = (o == i0) ? (1.0f / den)
                        : (o == i1) ? (dd / den) : 0.0f;

    if (!noiseLane) {
        out_sparse[(size_t)tok * NEXP + o] = sparsev;
        out_full  [(size_t)tok * NEXP + o] = fullv;
        if (o == 0) {
            out_ix[(size_t)tok * 2]     = (float)i0;
            out_ix[(size_t)tok * 2 + 1] = (float)i1;
        }
    }
}

extern "C" void kernel_launch(void* const* d_in, const int* in_sizes, int n_in,
                              void* d_out, int out_size, void* d_ws, size_t ws_size,
                              hipStream_t stream) {
    const float* h   = (const float*)d_in[0];
    const float* Ww  = (const float*)d_in[1];
    const float* bw  = (const float*)d_in[2];
    const float* Wn  = (const float*)d_in[3];
    const float* bn  = (const float*)d_in[4];
    const float* eps = (const float*)d_in[5];
    // d_in[6] = top_k (always 2 for this problem)

    float* out_sparse = (float*)d_out;                         // [T, 8]
    float* out_ix     = out_sparse + (size_t)NTOK * NEXP;      // [T, 2] (as float)
    float* out_full   = out_ix + (size_t)NTOK * 2;             // [T, 8]

    const int grid = NTOK / (TT * WPB);  // 2048 blocks x 256 threads
    noisy_topk_router<<<grid, 256, 0, stream>>>(h, Ww, bw, Wn, bn, eps,
                                                out_sparse, out_ix, out_full);
}